// Round 5
// baseline (338.814 us; speedup 1.0000x reference)
//
#include <hip/hip_runtime.h>
#include <hip/hip_bf16.h>
#include <stdint.h>

#define TOKENS 8192
#define IN_F   4096
#define OUT_F  4096
#define RANK   512

typedef __attribute__((ext_vector_type(8))) __bf16 bf16x8;
typedef __attribute__((ext_vector_type(4))) float f32x4;
typedef __attribute__((ext_vector_type(4))) short short4v;

static __device__ __forceinline__ unsigned short f2bf(float f) {
  union { float f; unsigned u; } v; v.f = f;
  return (unsigned short)((v.u + 0x7FFFu + ((v.u >> 16) & 1u)) >> 16);
}

static __device__ __forceinline__ void gload_lds16(const void* g, void* l) {
  __builtin_amdgcn_global_load_lds(
      (const __attribute__((address_space(1))) unsigned*)g,
      (__attribute__((address_space(3))) unsigned*)l, 16, 0, 0);
}

// ---------------------------------------------------------------------------
// Kernel 0 (fused prep): blocks [0,512) convert x f32->bf16;
// blocks [512,1536) build combined weight
//   M[o,i] = q[o,i]*scale + min_val + sum_r U[o,r]*S[r]*V[i,r]   (bf16)
// ---------------------------------------------------------------------------
__global__ __launch_bounds__(256) void prep_fused(
    const float* __restrict__ x, unsigned short* __restrict__ xb,
    const float* __restrict__ U, const float* __restrict__ V,
    const float* __restrict__ S, const int* __restrict__ q,
    const float* __restrict__ scale_p, const float* __restrict__ minv_p,
    unsigned short* __restrict__ M) {
  __shared__ unsigned short lA[128 * 64];
  __shared__ unsigned short lB[128 * 64];

  if (blockIdx.x < 512) {
    const int n4 = TOKENS * IN_F / 4;
    int idx = blockIdx.x * 256 + threadIdx.x;
    const int stride = 512 * 256;
    for (int i = idx; i < n4; i += stride) {
      f32x4 v = ((const f32x4*)x)[i];
      short4v o;
      o.x = (short)f2bf(v.x);
      o.y = (short)f2bf(v.y);
      o.z = (short)f2bf(v.z);
      o.w = (short)f2bf(v.w);
      ((short4v*)xb)[i] = o;
    }
    return;
  }

  const int bid  = blockIdx.x - 512;  // 0..1023
  const int tid  = threadIdx.x;
  const int wid  = tid >> 6;
  const int lane = tid & 63;
  const int bm = bid >> 5;
  const int bn = bid & 31;
  const int wm = (wid >> 1) * 64;
  const int wn = (wid & 1) * 64;

  f32x4 acc[4][4] = {};

  const int sr = tid >> 4;
  const int sc = (tid & 15) * 4;

  for (int k0 = 0; k0 < RANK; k0 += 64) {
    __syncthreads();
#pragma unroll
    for (int p = 0; p < 8; ++p) {
      int row = p * 16 + sr;
      f32x4 uv = *(const f32x4*)&U[(size_t)(bm * 128 + row) * RANK + k0 + sc];
      short4v pa;
      pa.x = (short)f2bf(uv.x); pa.y = (short)f2bf(uv.y);
      pa.z = (short)f2bf(uv.z); pa.w = (short)f2bf(uv.w);
      *(short4v*)&lA[row * 64 + sc] = pa;
      f32x4 vv = *(const f32x4*)&V[(size_t)(bn * 128 + row) * RANK + k0 + sc];
      f32x4 sv = *(const f32x4*)&S[k0 + sc];
      short4v pb;
      pb.x = (short)f2bf(vv.x * sv.x); pb.y = (short)f2bf(vv.y * sv.y);
      pb.z = (short)f2bf(vv.z * sv.z); pb.w = (short)f2bf(vv.w * sv.w);
      *(short4v*)&lB[row * 64 + sc] = pb;
    }
    __syncthreads();
#pragma unroll
    for (int kk = 0; kk < 2; ++kk) {
      bf16x8 af[4], bfr[4];
#pragma unroll
      for (int m = 0; m < 4; ++m)
        af[m] = *(const bf16x8*)&lA[(wm + m * 16 + (lane & 15)) * 64 + kk * 32 + (lane >> 4) * 8];
#pragma unroll
      for (int n = 0; n < 4; ++n)
        bfr[n] = *(const bf16x8*)&lB[(wn + n * 16 + (lane & 15)) * 64 + kk * 32 + (lane >> 4) * 8];
#pragma unroll
      for (int m = 0; m < 4; ++m)
#pragma unroll
        for (int n = 0; n < 4; ++n)
          acc[m][n] = __builtin_amdgcn_mfma_f32_16x16x32_bf16(af[m], bfr[n], acc[m][n], 0, 0, 0);
    }
  }

  const float scale = *scale_p;
  const float minv  = *minv_p;
  const int o0 = bm * 128 + wm;
  const int i0 = bn * 128 + wn;
#pragma unroll
  for (int m = 0; m < 4; ++m) {
#pragma unroll
    for (int n = 0; n < 4; ++n) {
      int col = i0 + n * 16 + (lane & 15);
#pragma unroll
      for (int rr = 0; rr < 4; ++rr) {
        int row = o0 + m * 16 + (lane >> 4) * 4 + rr;
        float dq = (float)q[(size_t)row * IN_F + col] * scale + minv;
        M[(size_t)row * IN_F + col] = f2bf(acc[m][n][rr] + dq);
      }
    }
  }
}

// ---------------------------------------------------------------------------
// Kernel 2: main GEMM, 256x256 tile, BK=64, 8 waves, 4 phases/K-tile,
// counted vmcnt(6), st-swizzled LDS, setprio, CROSS-PHASE FRAGMENT PREFETCH:
//   ph1 Q00(aA,b0): sync-read b0; prefetch aB[0,1] under MFMA
//   ph2 Q01(aA,b1): sync-read b1; prefetch aB[2,3] under MFMA
//   ph3 Q11(aB,b1): no reads
//   ph4 Q10(aB,b0): after vmcnt(6)+barrier, prefetch aA(t+1) under MFMA
// A-half0 frags (aA) always arrive via ph4 prefetch (prologue seeds t0).
// Landing proofs: aA(t+1) region staged ph2(t-1); at ph4(t)'s vmcnt(6) the
// in-flight set is exactly t+2.{A0,B0,B1} -> t+1 fully landed. aB(t) staged
// ph1(t-1), landed by ph4(t-1) drain; its region overwritten only ph1(t+1).
// Staging during tile t: ph1 -> t+1.A1 (buf qb); ph2 -> t+2.A0 (buf pb);
// ph3 -> t+2.B0; ph4 -> t+2.B1. 8 gloads/wave/tile; vmcnt(6) at ph4 retires
// exactly tile t+1's 8 loads.
// ---------------------------------------------------------------------------
__global__ __launch_bounds__(512, 2) void gemm256(
    const unsigned short* __restrict__ xb,
    const unsigned short* __restrict__ Mw,
    float* __restrict__ out) {
  extern __shared__ __align__(128) char smem[];
  const int tid  = threadIdx.x;
  const int wid  = tid >> 6;
  const int lane = tid & 63;
  const int wqm  = wid >> 2;  // 0..1 : 64-row slice within a 128x128 quadrant
  const int wqn  = wid & 3;   // 0..3 : 32-col slice

  // XCD-aware bijective swizzle (nwg = 512, divisible by 8)
  const int swz = (blockIdx.x & 7) * 64 + (blockIdx.x >> 3);
  const int bm = swz >> 4;   // 0..31 token tiles
  const int bn = swz & 15;   // 0..15 out-feature tiles
  const int row0 = bm * 256;
  const int col0 = bn * 256;

  // Per-lane ds_read byte offsets within an A/B half-tile (swizzle folded in).
  int offA[4][2], offB[2][2];
#pragma unroll
  for (int m = 0; m < 4; ++m)
#pragma unroll
    for (int kk = 0; kk < 2; ++kk) {
      int r = wqm * 64 + m * 16 + (lane & 15);
      int cb = kk * 64 + (lane >> 4) * 16;
      offA[m][kk] = r * 128 + (cb ^ ((r & 7) << 4));
    }
#pragma unroll
  for (int n = 0; n < 2; ++n)
#pragma unroll
    for (int kk = 0; kk < 2; ++kk) {
      int r = wqn * 32 + n * 16 + (lane & 15);
      int cb = kk * 64 + (lane >> 4) * 16;
      offB[n][kk] = r * 128 + (cb ^ ((r & 7) << 4));
    }

  // Pre-swizzled global source column (elements) for staging.
  const int sco = (((lane & 7) ^ (lane >> 3)) << 3);
  const int srw = lane >> 3;

  auto STAGE = [&](const unsigned short* __restrict__ src, int g0, int k0,
                   unsigned lb) {
#pragma unroll
    for (int j = 0; j < 2; ++j) {
      int r = (wid * 2 + j) * 8;
      const unsigned short* g =
          src + (size_t)(g0 + r + srw) * IN_F + k0 + sco;
      gload_lds16(g, smem + lb + r * 128);
    }
  };

  f32x4 acc[4][4][2] = {};  // [quadrant][m][n]
  bf16x8 aA[4][2], aB[4][2], b0[2][2], b1[2][2];

  // ---- prologue: tile0 all 4 halves -> buf0; tile1 A0,B0,B1 -> buf1 ----
  STAGE(xb, row0,       0, 0u);          // t0 A0
  STAGE(Mw, col0,       0, 32768u);      // t0 B0
  STAGE(Mw, col0 + 128, 0, 49152u);      // t0 B1
  STAGE(xb, row0 + 128, 0, 16384u);      // t0 A1
  STAGE(xb, row0,       64, 65536u);     // t1 A0
  STAGE(Mw, col0,       64, 98304u);     // t1 B0
  STAGE(Mw, col0 + 128, 64, 114688u);    // t1 B1
  asm volatile("s_waitcnt vmcnt(6)");    // tile0 landed; t1 A0/B0/B1 in flight
  __builtin_amdgcn_sched_barrier(0);
  __builtin_amdgcn_s_barrier();
  // seed aA(t0) (ph4-style prefetch)
#pragma unroll
  for (int m = 0; m < 4; ++m)
#pragma unroll
    for (int kk = 0; kk < 2; ++kk)
      aA[m][kk] = *(const bf16x8*)(smem + offA[m][kk]);

  const int nK = IN_F / 64;  // 64

  for (int t = 0; t < nK; ++t) {
    const unsigned pb = (unsigned)(t & 1) * 65536u;
    const unsigned qb = 65536u - pb;
    const int k1 = (t + 1) * 64;
    const int k2 = (t + 2) * 64;

    // ================= phase 1 : Q00 (aA, b0) =================
#pragma unroll
    for (int n = 0; n < 2; ++n)
#pragma unroll
      for (int kk = 0; kk < 2; ++kk)
        b0[n][kk] = *(const bf16x8*)(smem + pb + 32768u + offB[n][kk]);
    if (t + 1 < nK) STAGE(xb, row0 + 128, k1, qb + 16384u);  // t+1 A1
    __builtin_amdgcn_s_barrier();
    asm volatile("s_waitcnt lgkmcnt(0)");
    __builtin_amdgcn_sched_barrier(0);
#pragma unroll
    for (int m = 0; m < 2; ++m)  // prefetch aB[0,1]
#pragma unroll
      for (int kk = 0; kk < 2; ++kk)
        aB[m][kk] = *(const bf16x8*)(smem + pb + 16384u + offA[m][kk]);
    __builtin_amdgcn_sched_barrier(0);
    __builtin_amdgcn_s_setprio(1);
#pragma unroll
    for (int kk = 0; kk < 2; ++kk)
#pragma unroll
      for (int m = 0; m < 4; ++m)
#pragma unroll
        for (int n = 0; n < 2; ++n)
          acc[0][m][n] = __builtin_amdgcn_mfma_f32_16x16x32_bf16(
              aA[m][kk], b0[n][kk], acc[0][m][n], 0, 0, 0);
    __builtin_amdgcn_s_setprio(0);
    __builtin_amdgcn_sched_barrier(0);
    __builtin_amdgcn_s_barrier();

    // ================= phase 2 : Q01 (aA, b1) =================
#pragma unroll
    for (int n = 0; n < 2; ++n)
#pragma unroll
      for (int kk = 0; kk < 2; ++kk)
        b1[n][kk] = *(const bf16x8*)(smem + pb + 49152u + offB[n][kk]);
    if (t + 2 < nK) STAGE(xb, row0, k2, pb);  // t+2 A0
    __builtin_amdgcn_s_barrier();
    asm volatile("s_waitcnt lgkmcnt(0)");
    __builtin_amdgcn_sched_barrier(0);
#pragma unroll
    for (int m = 2; m < 4; ++m)  // prefetch aB[2,3]
#pragma unroll
      for (int kk = 0; kk < 2; ++kk)
        aB[m][kk] = *(const bf16x8*)(smem + pb + 16384u + offA[m][kk]);
    __builtin_amdgcn_sched_barrier(0);
    __builtin_amdgcn_s_setprio(1);
#pragma unroll
    for (int kk = 0; kk < 2; ++kk)
#pragma unroll
      for (int m = 0; m < 4; ++m)
#pragma unroll
        for (int n = 0; n < 2; ++n)
          acc[1][m][n] = __builtin_amdgcn_mfma_f32_16x16x32_bf16(
              aA[m][kk], b1[n][kk], acc[1][m][n], 0, 0, 0);
    __builtin_amdgcn_s_setprio(0);
    __builtin_amdgcn_sched_barrier(0);
    __builtin_amdgcn_s_barrier();

    // ================= phase 3 : Q11 (aB, b1) =================
    if (t + 2 < nK) STAGE(Mw, col0, k2, pb + 32768u);  // t+2 B0
    __builtin_amdgcn_s_barrier();
    asm volatile("s_waitcnt lgkmcnt(0)");
    __builtin_amdgcn_sched_barrier(0);
    __builtin_amdgcn_s_setprio(1);
#pragma unroll
    for (int kk = 0; kk < 2; ++kk)
#pragma unroll
      for (int m = 0; m < 4; ++m)
#pragma unroll
        for (int n = 0; n < 2; ++n)
          acc[2][m][n] = __builtin_amdgcn_mfma_f32_16x16x32_bf16(
              aB[m][kk], b1[n][kk], acc[2][m][n], 0, 0, 0);
    __builtin_amdgcn_s_setprio(0);
    __builtin_amdgcn_sched_barrier(0);
    __builtin_amdgcn_s_barrier();

    // ================= phase 4 : Q10 (aB, b0) =================
    if (t + 2 < nK) {
      STAGE(Mw, col0 + 128, k2, pb + 49152u);  // t+2 B1
      asm volatile("s_waitcnt vmcnt(6)");      // tile t+1 fully landed
    } else if (t + 1 < nK) {
      asm volatile("s_waitcnt vmcnt(0)");      // epilogue drain
    }
    __builtin_amdgcn_sched_barrier(0);
    __builtin_amdgcn_s_barrier();
    if (t + 1 < nK) {
      // prefetch aA(t+1) from buffer qb (landed by the drain above)
#pragma unroll
      for (int m = 0; m < 4; ++m)
#pragma unroll
        for (int kk = 0; kk < 2; ++kk)
          aA[m][kk] = *(const bf16x8*)(smem + qb + offA[m][kk]);
    }
    __builtin_amdgcn_sched_barrier(0);
    __builtin_amdgcn_s_setprio(1);
#pragma unroll
    for (int kk = 0; kk < 2; ++kk)
#pragma unroll
      for (int m = 0; m < 4; ++m)
#pragma unroll
        for (int n = 0; n < 2; ++n)
          acc[3][m][n] = __builtin_amdgcn_mfma_f32_16x16x32_bf16(
              aB[m][kk], b0[n][kk], acc[3][m][n], 0, 0, 0);
    __builtin_amdgcn_s_setprio(0);
    __builtin_amdgcn_sched_barrier(0);
    __builtin_amdgcn_s_barrier();
  }

  // ---- epilogue ----
  const int qm_[4] = {0, 0, 1, 1};
  const int qn_[4] = {0, 1, 1, 0};
#pragma unroll
  for (int q = 0; q < 4; ++q) {
#pragma unroll
    for (int m = 0; m < 4; ++m) {
#pragma unroll
      for (int n = 0; n < 2; ++n) {
        int col = col0 + qn_[q] * 128 + wqn * 32 + n * 16 + (lane & 15);
#pragma unroll
        for (int rr = 0; rr < 4; ++rr) {
          int row = row0 + qm_[q] * 128 + wqm * 64 + m * 16 + (lane >> 4) * 4 + rr;
          out[(size_t)row * OUT_F + col] = acc[q][m][n][rr];
        }
      }
    }
  }
}

// ---------------------------------------------------------------------------
// Fallback main GEMM (128^2, used only if ws < 96 MB): A reg-staged from f32.
// ---------------------------------------------------------------------------
__global__ __launch_bounds__(256) void gemm_main_f(const float* __restrict__ xf,
                                                   const unsigned short* __restrict__ Mw,
                                                   float* __restrict__ out) {
  __shared__ unsigned short lA[128 * 64];
  __shared__ unsigned short lB[128 * 64];
  const int tid  = threadIdx.x;
  const int wid  = tid >> 6;
  const int lane = tid & 63;
  const int nwg = gridDim.x;
  const int cpx = nwg >> 3;
  const int swz = (blockIdx.x & 7) * cpx + (blockIdx.x >> 3);
  const int bm = swz >> 5;
  const int bn = swz & 31;
  const int wm = (wid >> 1) * 64;
  const int wn = (wid & 1) * 64;
  const int row0 = bm * 128;
  const int col0 = bn * 128;

  f32x4 acc[4][4] = {};

  for (int k0 = 0; k0 < IN_F; k0 += 64) {
    __syncthreads();
    const int sr = tid >> 4;
    const int sc = (tid & 15) * 4;
#pragma unroll
    for (int p = 0; p < 8; ++p) {
      int row = p * 16 + sr;
      f32x4 v = *(const f32x4*)&xf[(size_t)(row0 + row) * IN_F + k0 + sc];
      short4v pa;
      pa.x = (short)f2bf(v.x); pa.y = (short)f2bf(v.y);
      pa.z = (short)f2bf(v.z); pa.w = (short)f2bf(v.w);
      *(short4v*)&lA[row * 64 + sc] = pa;
    }
#pragma unroll
    for (int j = 0; j < 4; ++j) {
      int rbase = (wid * 4 + j) * 8;
      const unsigned short* src =
          &Mw[(size_t)(col0 + rbase + (lane >> 3)) * IN_F + k0 + (lane & 7) * 8];
      gload_lds16(src, &lB[rbase * 64]);
    }
    __syncthreads();
#pragma unroll
    for (int kk = 0; kk < 2; ++kk) {
      bf16x8 af[4], bfr[4];
#pragma unroll
      for (int m = 0; m < 4; ++m)
        af[m] = *(const bf16x8*)&lA[(wm + m * 16 + (lane & 15)) * 64 + kk * 32 + (lane >> 4) * 8];
#pragma unroll
      for (int n = 0; n < 4; ++n)
        bfr[n] = *(const bf16x8*)&lB[(wn + n * 16 + (lane & 15)) * 64 + kk * 32 + (lane >> 4) * 8];
#pragma unroll
      for (int m = 0; m < 4; ++m)
#pragma unroll
        for (int n = 0; n < 4; ++n)
          acc[m][n] = __builtin_amdgcn_mfma_f32_16x16x32_bf16(af[m], bfr[n], acc[m][n], 0, 0, 0);
    }
  }

#pragma unroll
  for (int m = 0; m < 4; ++m) {
#pragma unroll
    for (int n = 0; n < 4; ++n) {
      int col = col0 + wn + n * 16 + (lane & 15);
#pragma unroll
      for (int rr = 0; rr < 4; ++rr) {
        int row = row0 + wm + m * 16 + (lane >> 4) * 4 + rr;
        out[(size_t)row * OUT_F + col] = acc[m][n][rr];
      }
    }
  }
}

// ---------------------------------------------------------------------------
extern "C" void kernel_launch(void* const* d_in, const int* in_sizes, int n_in,
                              void* d_out, int out_size, void* d_ws, size_t ws_size,
                              hipStream_t stream) {
  const float* x      = (const float*)d_in[0];
  const int*   q      = (const int*)d_in[1];
  const float* scale  = (const float*)d_in[2];
  const float* minv   = (const float*)d_in[3];
  const float* U      = (const float*)d_in[4];
  const float* S      = (const float*)d_in[5];
  const float* V      = (const float*)d_in[6];
  float* out = (float*)d_out;

  const size_t xb_bytes = (size_t)TOKENS * IN_F * 2;  // 64 MB
  const size_t m_bytes  = (size_t)OUT_F * IN_F * 2;   // 32 MB

  if (ws_size >= xb_bytes + m_bytes) {
    unsigned short* xbuf = (unsigned short*)d_ws;
    unsigned short* Mw   = (unsigned short*)((char*)d_ws + xb_bytes);
    (void)hipFuncSetAttribute((const void*)gemm256,
                              hipFuncAttributeMaxDynamicSharedMemorySize,
                              131072);
    prep_fused<<<dim3(1536), dim3(256), 0, stream>>>(x, xbuf, U, V, S, q,
                                                     scale, minv, Mw);
    gemm256<<<dim3(512), dim3(512), 131072, stream>>>(xbuf, Mw, out);
  } else {
    unsigned short* Mw = (unsigned short*)d_ws;  // needs 32 MB
    prep_fused<<<dim3(1536), dim3(256), 0, stream>>>(nullptr, nullptr, U, V, S,
                                                     q, scale, minv, Mw);
    gemm_main_f<<<dim3(2048), dim3(256), 0, stream>>>(x, Mw, out);
  }
}

// Round 6
// 334.966 us; speedup vs baseline: 1.0115x; 1.0115x over previous
//
#include <hip/hip_runtime.h>
#include <hip/hip_bf16.h>
#include <stdint.h>

#define TOKENS 8192
#define IN_F   4096
#define OUT_F  4096
#define RANK   512

typedef __attribute__((ext_vector_type(8))) __bf16 bf16x8;
typedef __attribute__((ext_vector_type(4))) float f32x4;
typedef __attribute__((ext_vector_type(4))) short short4v;

static __device__ __forceinline__ unsigned short f2bf(float f) {
  union { float f; unsigned u; } v; v.f = f;
  return (unsigned short)((v.u + 0x7FFFu + ((v.u >> 16) & 1u)) >> 16);
}

static __device__ __forceinline__ void gload_lds16(const void* g, void* l) {
  __builtin_amdgcn_global_load_lds(
      (const __attribute__((address_space(1))) unsigned*)g,
      (__attribute__((address_space(3))) unsigned*)l, 16, 0, 0);
}

// ---------------------------------------------------------------------------
// Kernel 0 (fused prep): blocks [0,512) convert x f32->bf16;
// blocks [512,1536) build combined weight
//   M[o,i] = q[o,i]*scale + min_val + sum_r U[o,r]*S[r]*V[i,r]   (bf16)
// ---------------------------------------------------------------------------
__global__ __launch_bounds__(256) void prep_fused(
    const float* __restrict__ x, unsigned short* __restrict__ xb,
    const float* __restrict__ U, const float* __restrict__ V,
    const float* __restrict__ S, const int* __restrict__ q,
    const float* __restrict__ scale_p, const float* __restrict__ minv_p,
    unsigned short* __restrict__ M) {
  __shared__ unsigned short lA[128 * 64];
  __shared__ unsigned short lB[128 * 64];

  if (blockIdx.x < 512) {
    const int n4 = TOKENS * IN_F / 4;
    int idx = blockIdx.x * 256 + threadIdx.x;
    const int stride = 512 * 256;
    for (int i = idx; i < n4; i += stride) {
      f32x4 v = ((const f32x4*)x)[i];
      short4v o;
      o.x = (short)f2bf(v.x);
      o.y = (short)f2bf(v.y);
      o.z = (short)f2bf(v.z);
      o.w = (short)f2bf(v.w);
      ((short4v*)xb)[i] = o;
    }
    return;
  }

  const int bid  = blockIdx.x - 512;  // 0..1023
  const int tid  = threadIdx.x;
  const int wid  = tid >> 6;
  const int lane = tid & 63;
  const int bm = bid >> 5;
  const int bn = bid & 31;
  const int wm = (wid >> 1) * 64;
  const int wn = (wid & 1) * 64;

  f32x4 acc[4][4] = {};

  const int sr = tid >> 4;
  const int sc = (tid & 15) * 4;

  for (int k0 = 0; k0 < RANK; k0 += 64) {
    __syncthreads();
#pragma unroll
    for (int p = 0; p < 8; ++p) {
      int row = p * 16 + sr;
      f32x4 uv = *(const f32x4*)&U[(size_t)(bm * 128 + row) * RANK + k0 + sc];
      short4v pa;
      pa.x = (short)f2bf(uv.x); pa.y = (short)f2bf(uv.y);
      pa.z = (short)f2bf(uv.z); pa.w = (short)f2bf(uv.w);
      *(short4v*)&lA[row * 64 + sc] = pa;
      f32x4 vv = *(const f32x4*)&V[(size_t)(bn * 128 + row) * RANK + k0 + sc];
      f32x4 sv = *(const f32x4*)&S[k0 + sc];
      short4v pb;
      pb.x = (short)f2bf(vv.x * sv.x); pb.y = (short)f2bf(vv.y * sv.y);
      pb.z = (short)f2bf(vv.z * sv.z); pb.w = (short)f2bf(vv.w * sv.w);
      *(short4v*)&lB[row * 64 + sc] = pb;
    }
    __syncthreads();
#pragma unroll
    for (int kk = 0; kk < 2; ++kk) {
      bf16x8 af[4], bfr[4];
#pragma unroll
      for (int m = 0; m < 4; ++m)
        af[m] = *(const bf16x8*)&lA[(wm + m * 16 + (lane & 15)) * 64 + kk * 32 + (lane >> 4) * 8];
#pragma unroll
      for (int n = 0; n < 4; ++n)
        bfr[n] = *(const bf16x8*)&lB[(wn + n * 16 + (lane & 15)) * 64 + kk * 32 + (lane >> 4) * 8];
#pragma unroll
      for (int m = 0; m < 4; ++m)
#pragma unroll
        for (int n = 0; n < 4; ++n)
          acc[m][n] = __builtin_amdgcn_mfma_f32_16x16x32_bf16(af[m], bfr[n], acc[m][n], 0, 0, 0);
    }
  }

  const float scale = *scale_p;
  const float minv  = *minv_p;
  const int o0 = bm * 128 + wm;
  const int i0 = bn * 128 + wn;
#pragma unroll
  for (int m = 0; m < 4; ++m) {
#pragma unroll
    for (int n = 0; n < 4; ++n) {
      int col = i0 + n * 16 + (lane & 15);
#pragma unroll
      for (int rr = 0; rr < 4; ++rr) {
        int row = o0 + m * 16 + (lane >> 4) * 4 + rr;
        float dq = (float)q[(size_t)row * IN_F + col] * scale + minv;
        M[(size_t)row * IN_F + col] = f2bf(acc[m][n][rr] + dq);
      }
    }
  }
}

// ---------------------------------------------------------------------------
// small helpers for gemm256
// ---------------------------------------------------------------------------
static __device__ __forceinline__ void readA4(bf16x8 (&a)[4][2],
                                              const char* __restrict__ base,
                                              const int (&off)[4][2]) {
#pragma unroll
  for (int m = 0; m < 4; ++m)
#pragma unroll
    for (int kk = 0; kk < 2; ++kk)
      a[m][kk] = *(const bf16x8*)(base + off[m][kk]);
}
static __device__ __forceinline__ void readB2(bf16x8 (&b)[2][2],
                                              const char* __restrict__ base,
                                              const int (&off)[2][2]) {
#pragma unroll
  for (int n = 0; n < 2; ++n)
#pragma unroll
    for (int kk = 0; kk < 2; ++kk)
      b[n][kk] = *(const bf16x8*)(base + off[n][kk]);
}
static __device__ __forceinline__ void mfmaQ(f32x4 (&aq)[4][2],
                                             const bf16x8 (&a)[4][2],
                                             const bf16x8 (&b)[2][2]) {
#pragma unroll
  for (int m = 0; m < 4; ++m)
#pragma unroll
    for (int n = 0; n < 2; ++n)
#pragma unroll
      for (int kk = 0; kk < 2; ++kk)
        aq[m][n] = __builtin_amdgcn_mfma_f32_16x16x32_bf16(a[m][kk], b[n][kk],
                                                           aq[m][n], 0, 0, 0);
}

#define BARR()  __builtin_amdgcn_s_barrier()
#define SCHED() __builtin_amdgcn_sched_barrier(0)
#define LGKM0() asm volatile("s_waitcnt lgkmcnt(0)")
#define PRIO1() __builtin_amdgcn_s_setprio(1)
#define PRIO0() __builtin_amdgcn_s_setprio(0)

// ---------------------------------------------------------------------------
// Kernel 2: main GEMM, 256x256 tile, BK=64, 8 waves, st-swizzled LDS,
// counted vmcnt(6), setprio — BRANCH-FREE 2-K-TILE UNROLLED steady state.
// Each iteration processes tile tt (buf0) then tt+1 (buf1); all LDS/global
// addresses are loop-invariant bases + compile-time immediates. Staging
// schedule (identical invariants to round 2, relabeled):
//   ph1: (tt+1).A1 -> buf1+16384   ph5: (tt+2).A1 -> buf0+16384
//   ph2: (tt+2).A0 -> buf0+0       ph6: (tt+3).A0 -> buf1+0
//   ph3: (tt+2).B0 -> buf0+32768   ph7: (tt+3).B0 -> buf1+32768
//   ph4: (tt+2).B1 -> buf0+49152   ph8: (tt+3).B1 -> buf1+49152
// vmcnt(6) at ph4 retires (tt+1) fully; at ph8 retires (tt+2) fully.
// Main loop tt = 0..60 step 2 (31 iters); peeled tail = tiles 62, 63.
// ---------------------------------------------------------------------------
__global__ __launch_bounds__(512, 2) void gemm256(
    const unsigned short* __restrict__ xb,
    const unsigned short* __restrict__ Mw,
    float* __restrict__ out) {
  extern __shared__ __align__(128) char smem[];
  const int tid  = threadIdx.x;
  const int wid  = tid >> 6;
  const int lane = tid & 63;
  const int wqm  = wid >> 2;  // 0..1 : 64-row slice within a 128x128 quadrant
  const int wqn  = wid & 3;   // 0..3 : 32-col slice

  // XCD-aware bijective swizzle (nwg = 512, divisible by 8)
  const int swz = (blockIdx.x & 7) * 64 + (blockIdx.x >> 3);
  const int bm = swz >> 4;   // 0..31 token tiles
  const int bn = swz & 15;   // 0..15 out-feature tiles
  const int row0 = bm * 256;
  const int col0 = bn * 256;

  // Per-lane ds_read byte offsets within an A/B half-tile (swizzle folded in).
  int offA[4][2], offB[2][2];
#pragma unroll
  for (int m = 0; m < 4; ++m)
#pragma unroll
    for (int kk = 0; kk < 2; ++kk) {
      int r = wqm * 64 + m * 16 + (lane & 15);
      int cb = kk * 64 + (lane >> 4) * 16;
      offA[m][kk] = r * 128 + (cb ^ ((r & 7) << 4));
    }
#pragma unroll
  for (int n = 0; n < 2; ++n)
#pragma unroll
    for (int kk = 0; kk < 2; ++kk) {
      int r = wqn * 32 + n * 16 + (lane & 15);
      int cb = kk * 64 + (lane >> 4) * 16;
      offB[n][kk] = r * 128 + (cb ^ ((r & 7) << 4));
    }

  // Staging source pointers (pre-swizzled global column; advance += 128/iter)
  const int sco = (((lane & 7) ^ (lane >> 3)) << 3);
  const int srw = lane >> 3;
  const unsigned short* aP = xb + (size_t)(row0 + wid * 16 + srw) * IN_F + sco;
  const unsigned short* bP = Mw + (size_t)(col0 + wid * 16 + srw) * IN_F + sco;
  const unsigned short* aH = aP + (size_t)128 * IN_F;  // A rows +128
  const unsigned short* bH = bP + (size_t)128 * IN_F;  // B rows +128
  char* lw = smem + wid * 2048;  // wave's LDS staging slot within a region

  // stage 2x gload_lds (16 rows of a 128x64 half-tile per wave)
  auto STG = [&](const unsigned short* __restrict__ g, char* l) {
    gload_lds16(g, l);
    gload_lds16(g + 8 * IN_F, l + 1024);
  };

  f32x4 acc[4][4][2] = {};  // [quadrant][m][n]
  bf16x8 a[4][2], b0[2][2], b1[2][2];

  // ---- prologue: t0 {A0,B0,B1,A1} -> buf0; t1 {A0,B0,B1} -> buf1 ----
  STG(aP,       lw + 0);        // t0 A0
  STG(bP,       lw + 32768);    // t0 B0
  STG(bH,       lw + 49152);    // t0 B1
  STG(aH,       lw + 16384);    // t0 A1
  STG(aP + 64,  lw + 65536);    // t1 A0
  STG(bP + 64,  lw + 98304);    // t1 B0
  STG(bH + 64,  lw + 114688);   // t1 B1
  asm volatile("s_waitcnt vmcnt(6)");  // t0 landed; t1 (3 stages) in flight
  SCHED();
  BARR();

  // ---- main loop: 31 iterations, tiles 0..61 ----
  for (int it = 0; it < 31; ++it) {
    // ============ tile tt : buf0 ============
    // ph1 : Q00 (a=buf0.A0, b0=buf0.B0)
    readA4(a, smem, offA);
    readB2(b0, smem + 32768, offB);
    STG(aH + 64, lw + 81920);                 // (tt+1).A1 -> buf1.A1
    asm volatile("s_waitcnt lgkmcnt(8)");
    BARR(); LGKM0(); SCHED();
    PRIO1(); mfmaQ(acc[0], a, b0); PRIO0(); SCHED(); BARR();

    // ph2 : Q01 (b1=buf0.B1)
    readB2(b1, smem + 49152, offB);
    STG(aP + 128, lw + 0);                    // (tt+2).A0 -> buf0.A0
    BARR(); LGKM0(); SCHED();
    PRIO1(); mfmaQ(acc[1], a, b1); PRIO0(); SCHED(); BARR();

    // ph3 : Q11 (a=buf0.A1)
    readA4(a, smem + 16384, offA);
    STG(bP + 128, lw + 32768);                // (tt+2).B0 -> buf0.B0
    BARR(); LGKM0(); SCHED();
    PRIO1(); mfmaQ(acc[2], a, b1); PRIO0(); SCHED(); BARR();

    // ph4 : Q10
    STG(bH + 128, lw + 49152);                // (tt+2).B1 -> buf0.B1
    asm volatile("s_waitcnt vmcnt(6)");       // (tt+1) fully landed
    SCHED(); BARR();
    PRIO1(); mfmaQ(acc[3], a, b0); PRIO0(); SCHED(); BARR();

    // ============ tile tt+1 : buf1 ============
    // ph5 : Q00
    readA4(a, smem + 65536, offA);
    readB2(b0, smem + 98304, offB);
    STG(aH + 128, lw + 16384);                // (tt+2).A1 -> buf0.A1
    asm volatile("s_waitcnt lgkmcnt(8)");
    BARR(); LGKM0(); SCHED();
    PRIO1(); mfmaQ(acc[0], a, b0); PRIO0(); SCHED(); BARR();

    // ph6 : Q01
    readB2(b1, smem + 114688, offB);
    STG(aP + 192, lw + 65536);                // (tt+3).A0 -> buf1.A0
    BARR(); LGKM0(); SCHED();
    PRIO1(); mfmaQ(acc[1], a, b1); PRIO0(); SCHED(); BARR();

    // ph7 : Q11
    readA4(a, smem + 81920, offA);
    STG(bP + 192, lw + 98304);                // (tt+3).B0 -> buf1.B0
    BARR(); LGKM0(); SCHED();
    PRIO1(); mfmaQ(acc[2], a, b1); PRIO0(); SCHED(); BARR();

    // ph8 : Q10
    STG(bH + 192, lw + 114688);               // (tt+3).B1 -> buf1.B1
    asm volatile("s_waitcnt vmcnt(6)");       // (tt+2) fully landed
    SCHED(); BARR();
    PRIO1(); mfmaQ(acc[3], a, b0); PRIO0(); SCHED(); BARR();

    aP += 128; bP += 128; aH += 128; bH += 128;
  }

  // ---- peeled tail: tile 62 (buf0), tile 63 (buf1) ----
  // tile 62
  readA4(a, smem, offA);
  readB2(b0, smem + 32768, offB);
  STG(aH + 64, lw + 81920);                   // 63.A1 -> buf1.A1
  asm volatile("s_waitcnt lgkmcnt(8)");
  BARR(); LGKM0(); SCHED();
  PRIO1(); mfmaQ(acc[0], a, b0); PRIO0(); SCHED(); BARR();

  readB2(b1, smem + 49152, offB);
  BARR(); LGKM0(); SCHED();
  PRIO1(); mfmaQ(acc[1], a, b1); PRIO0(); SCHED(); BARR();

  readA4(a, smem + 16384, offA);
  BARR(); LGKM0(); SCHED();
  PRIO1(); mfmaQ(acc[2], a, b1); PRIO0(); SCHED(); BARR();

  asm volatile("s_waitcnt vmcnt(0)");         // drain: tile 63 fully landed
  SCHED(); BARR();
  PRIO1(); mfmaQ(acc[3], a, b0); PRIO0(); SCHED(); BARR();

  // tile 63
  readA4(a, smem + 65536, offA);
  readB2(b0, smem + 98304, offB);
  BARR(); LGKM0(); SCHED();
  PRIO1(); mfmaQ(acc[0], a, b0); PRIO0(); SCHED(); BARR();

  readB2(b1, smem + 114688, offB);
  BARR(); LGKM0(); SCHED();
  PRIO1(); mfmaQ(acc[1], a, b1); PRIO0(); SCHED(); BARR();

  readA4(a, smem + 81920, offA);
  BARR(); LGKM0(); SCHED();
  PRIO1(); mfmaQ(acc[2], a, b1); PRIO0(); SCHED();
  mfmaQ(acc[3], a, b0);

  // ---- epilogue ----
  const int qm_[4] = {0, 0, 1, 1};
  const int qn_[4] = {0, 1, 1, 0};
#pragma unroll
  for (int q = 0; q < 4; ++q) {
#pragma unroll
    for (int m = 0; m < 4; ++m) {
#pragma unroll
      for (int n = 0; n < 2; ++n) {
        int col = col0 + qn_[q] * 128 + wqn * 32 + n * 16 + (lane & 15);
#pragma unroll
        for (int rr = 0; rr < 4; ++rr) {
          int row = row0 + qm_[q] * 128 + wqm * 64 + m * 16 + (lane >> 4) * 4 + rr;
          out[(size_t)row * OUT_F + col] = acc[q][m][n][rr];
        }
      }
    }
  }
}

// ---------------------------------------------------------------------------
// Fallback main GEMM (128^2, used only if ws < 96 MB): A reg-staged from f32.
// ---------------------------------------------------------------------------
__global__ __launch_bounds__(256) void gemm_main_f(const float* __restrict__ xf,
                                                   const unsigned short* __restrict__ Mw,
                                                   float* __restrict__ out) {
  __shared__ unsigned short lA[128 * 64];
  __shared__ unsigned short lB[128 * 64];
  const int tid  = threadIdx.x;
  const int wid  = tid >> 6;
  const int lane = tid & 63;
  const int nwg = gridDim.x;
  const int cpx = nwg >> 3;
  const int swz = (blockIdx.x & 7) * cpx + (blockIdx.x >> 3);
  const int bm = swz >> 5;
  const int bn = swz & 31;
  const int wm = (wid >> 1) * 64;
  const int wn = (wid & 1) * 64;
  const int row0 = bm * 128;
  const int col0 = bn * 128;

  f32x4 acc[4][4] = {};

  for (int k0 = 0; k0 < IN_F; k0 += 64) {
    __syncthreads();
    const int sr = tid >> 4;
    const int sc = (tid & 15) * 4;
#pragma unroll
    for (int p = 0; p < 8; ++p) {
      int row = p * 16 + sr;
      f32x4 v = *(const f32x4*)&xf[(size_t)(row0 + row) * IN_F + k0 + sc];
      short4v pa;
      pa.x = (short)f2bf(v.x); pa.y = (short)f2bf(v.y);
      pa.z = (short)f2bf(v.z); pa.w = (short)f2bf(v.w);
      *(short4v*)&lA[row * 64 + sc] = pa;
    }
#pragma unroll
    for (int j = 0; j < 4; ++j) {
      int rbase = (wid * 4 + j) * 8;
      const unsigned short* src =
          &Mw[(size_t)(col0 + rbase + (lane >> 3)) * IN_F + k0 + (lane & 7) * 8];
      gload_lds16(src, &lB[rbase * 64]);
    }
    __syncthreads();
#pragma unroll
    for (int kk = 0; kk < 2; ++kk) {
      bf16x8 af[4], bfr[4];
#pragma unroll
      for (int m = 0; m < 4; ++m)
        af[m] = *(const bf16x8*)&lA[(wm + m * 16 + (lane & 15)) * 64 + kk * 32 + (lane >> 4) * 8];
#pragma unroll
      for (int n = 0; n < 4; ++n)
        bfr[n] = *(const bf16x8*)&lB[(wn + n * 16 + (lane & 15)) * 64 + kk * 32 + (lane >> 4) * 8];
#pragma unroll
      for (int m = 0; m < 4; ++m)
#pragma unroll
        for (int n = 0; n < 4; ++n)
          acc[m][n] = __builtin_amdgcn_mfma_f32_16x16x32_bf16(af[m], bfr[n], acc[m][n], 0, 0, 0);
    }
  }

#pragma unroll
  for (int m = 0; m < 4; ++m) {
#pragma unroll
    for (int n = 0; n < 4; ++n) {
      int col = col0 + wn + n * 16 + (lane & 15);
#pragma unroll
      for (int rr = 0; rr < 4; ++rr) {
        int row = row0 + wm + m * 16 + (lane >> 4) * 4 + rr;
        out[(size_t)row * OUT_F + col] = acc[m][n][rr];
      }
    }
  }
}

// ---------------------------------------------------------------------------
extern "C" void kernel_launch(void* const* d_in, const int* in_sizes, int n_in,
                              void* d_out, int out_size, void* d_ws, size_t ws_size,
                              hipStream_t stream) {
  const float* x      = (const float*)d_in[0];
  const int*   q      = (const int*)d_in[1];
  const float* scale  = (const float*)d_in[2];
  const float* minv   = (const float*)d_in[3];
  const float* U      = (const float*)d_in[4];
  const float* S      = (const float*)d_in[5];
  const float* V      = (const float*)d_in[6];
  float* out = (float*)d_out;

  const size_t xb_bytes = (size_t)TOKENS * IN_F * 2;  // 64 MB
  const size_t m_bytes  = (size_t)OUT_F * IN_F * 2;   // 32 MB

  if (ws_size >= xb_bytes + m_bytes) {
    unsigned short* xbuf = (unsigned short*)d_ws;
    unsigned short* Mw   = (unsigned short*)((char*)d_ws + xb_bytes);
    (void)hipFuncSetAttribute((const void*)gemm256,
                              hipFuncAttributeMaxDynamicSharedMemorySize,
                              131072);
    prep_fused<<<dim3(1536), dim3(256), 0, stream>>>(x, xbuf, U, V, S, q,
                                                     scale, minv, Mw);
    gemm256<<<dim3(512), dim3(512), 131072, stream>>>(xbuf, Mw, out);
  } else {
    unsigned short* Mw = (unsigned short*)d_ws;  // needs 32 MB
    prep_fused<<<dim3(1536), dim3(256), 0, stream>>>(nullptr, nullptr, U, V, S,
                                                     q, scale, minv, Mw);
    gemm_main_f<<<dim3(2048), dim3(256), 0, stream>>>(x, Mw, out);
  }
}

// Round 7
// 235.883 us; speedup vs baseline: 1.4364x; 1.4200x over previous
//
#include <hip/hip_runtime.h>
#include <hip/hip_bf16.h>
#include <stdint.h>

#define TOKENS 8192
#define IN_F   4096
#define OUT_F  4096
#define RANK   512

typedef __attribute__((ext_vector_type(8))) __bf16 bf16x8;
typedef __attribute__((ext_vector_type(4))) float f32x4;
typedef __attribute__((ext_vector_type(4))) short short4v;
typedef __attribute__((ext_vector_type(8))) short short8v;
typedef __attribute__((ext_vector_type(4))) int i32x4;

static __device__ __forceinline__ unsigned short f2bf(float f) {
  union { float f; unsigned u; } v; v.f = f;
  return (unsigned short)((v.u + 0x7FFFu + ((v.u >> 16) & 1u)) >> 16);
}
static __device__ __forceinline__ float bf2f(unsigned short us) {
  union { unsigned u; float f; } v; v.u = ((unsigned)us) << 16;
  return v.f;
}

static __device__ __forceinline__ void gload_lds16(const void* g, void* l) {
  __builtin_amdgcn_global_load_lds(
      (const __attribute__((address_space(1))) unsigned*)g,
      (__attribute__((address_space(3))) unsigned*)l, 16, 0, 0);
}

// ---------------------------------------------------------------------------
// prep1: blocks [0,1024) build combined weight M (bf16):
//   M[o,i] = q[o,i]*scale + min_val + sum_r U[o,r]*S[r]*V[i,r]
// blocks [1024, 9216): per-token symmetric int8 quantization of x
//   (row absmax -> xi8, sx[t] = amax/127)
// ---------------------------------------------------------------------------
__global__ __launch_bounds__(256) void prep1(
    const float* __restrict__ x, char* __restrict__ xi8, float* __restrict__ sx,
    const float* __restrict__ U, const float* __restrict__ V,
    const float* __restrict__ S, const int* __restrict__ q,
    const float* __restrict__ scale_p, const float* __restrict__ minv_p,
    unsigned short* __restrict__ M) {
  __shared__ unsigned short lA[128 * 64];
  __shared__ unsigned short lB[128 * 64];
  __shared__ float red[4];

  if (blockIdx.x >= 1024) {
    // ---- quant_x: one block per token row ----
    const int row = blockIdx.x - 1024;
    const int t = threadIdx.x;
    const float* xr = x + (size_t)row * IN_F;
    f32x4 v[4];
    float am = 0.f;
#pragma unroll
    for (int j = 0; j < 4; ++j) {
      v[j] = *(const f32x4*)&xr[t * 16 + j * 4];
#pragma unroll
      for (int e = 0; e < 4; ++e) am = fmaxf(am, fabsf(v[j][e]));
    }
#pragma unroll
    for (int s = 32; s; s >>= 1) am = fmaxf(am, __shfl_xor(am, s));
    if ((t & 63) == 0) red[t >> 6] = am;
    __syncthreads();
    am = fmaxf(fmaxf(red[0], red[1]), fmaxf(red[2], red[3]));
    am = fmaxf(am, 1e-12f);
    const float inv = 127.0f / am;
    i32x4 pk;
#pragma unroll
    for (int j = 0; j < 4; ++j) {
      unsigned p = 0;
#pragma unroll
      for (int e = 0; e < 4; ++e) {
        float qf = rintf(v[j][e] * inv);
        qf = fminf(fmaxf(qf, -127.f), 127.f);
        p |= ((unsigned)((int)qf & 0xFF)) << (8 * e);
      }
      pk[j] = (int)p;
    }
    *(i32x4*)&xi8[(size_t)row * IN_F + t * 16] = pk;
    if (t == 0) sx[row] = am * (1.0f / 127.0f);
    return;
  }

  // ---- build_m ----
  const int bid  = blockIdx.x;  // 0..1023
  const int tid  = threadIdx.x;
  const int wid  = tid >> 6;
  const int lane = tid & 63;
  const int bm = bid >> 5;
  const int bn = bid & 31;
  const int wm = (wid >> 1) * 64;
  const int wn = (wid & 1) * 64;

  f32x4 acc[4][4] = {};

  const int sr = tid >> 4;
  const int sc = (tid & 15) * 4;

  for (int k0 = 0; k0 < RANK; k0 += 64) {
    __syncthreads();
#pragma unroll
    for (int p = 0; p < 8; ++p) {
      int row = p * 16 + sr;
      f32x4 uv = *(const f32x4*)&U[(size_t)(bm * 128 + row) * RANK + k0 + sc];
      short4v pa;
      pa.x = (short)f2bf(uv.x); pa.y = (short)f2bf(uv.y);
      pa.z = (short)f2bf(uv.z); pa.w = (short)f2bf(uv.w);
      *(short4v*)&lA[row * 64 + sc] = pa;
      f32x4 vv = *(const f32x4*)&V[(size_t)(bn * 128 + row) * RANK + k0 + sc];
      f32x4 sv = *(const f32x4*)&S[k0 + sc];
      short4v pb;
      pb.x = (short)f2bf(vv.x * sv.x); pb.y = (short)f2bf(vv.y * sv.y);
      pb.z = (short)f2bf(vv.z * sv.z); pb.w = (short)f2bf(vv.w * sv.w);
      *(short4v*)&lB[row * 64 + sc] = pb;
    }
    __syncthreads();
#pragma unroll
    for (int kk = 0; kk < 2; ++kk) {
      bf16x8 af[4], bfr[4];
#pragma unroll
      for (int m = 0; m < 4; ++m)
        af[m] = *(const bf16x8*)&lA[(wm + m * 16 + (lane & 15)) * 64 + kk * 32 + (lane >> 4) * 8];
#pragma unroll
      for (int n = 0; n < 4; ++n)
        bfr[n] = *(const bf16x8*)&lB[(wn + n * 16 + (lane & 15)) * 64 + kk * 32 + (lane >> 4) * 8];
#pragma unroll
      for (int m = 0; m < 4; ++m)
#pragma unroll
        for (int n = 0; n < 4; ++n)
          acc[m][n] = __builtin_amdgcn_mfma_f32_16x16x32_bf16(af[m], bfr[n], acc[m][n], 0, 0, 0);
    }
  }

  const float scale = *scale_p;
  const float minv  = *minv_p;
  const int o0 = bm * 128 + wm;
  const int i0 = bn * 128 + wn;
#pragma unroll
  for (int m = 0; m < 4; ++m) {
#pragma unroll
    for (int n = 0; n < 4; ++n) {
      int col = i0 + n * 16 + (lane & 15);
#pragma unroll
      for (int rr = 0; rr < 4; ++rr) {
        int row = o0 + m * 16 + (lane >> 4) * 4 + rr;
        float dq = (float)q[(size_t)row * IN_F + col] * scale + minv;
        M[(size_t)row * IN_F + col] = f2bf(acc[m][n][rr] + dq);
      }
    }
  }
}

// ---------------------------------------------------------------------------
// prep2: per-output-row symmetric int8 quantization of M (bf16 -> i8 + sm[o])
// ---------------------------------------------------------------------------
__global__ __launch_bounds__(256) void prep2(const unsigned short* __restrict__ M,
                                             char* __restrict__ mi8,
                                             float* __restrict__ sm) {
  __shared__ float red[4];
  const int row = blockIdx.x;
  const int t = threadIdx.x;
  const unsigned short* mr = M + (size_t)row * IN_F;
  float v[16];
  float am = 0.f;
#pragma unroll
  for (int j = 0; j < 2; ++j) {
    short8v h = *(const short8v*)&mr[t * 16 + j * 8];
#pragma unroll
    for (int e = 0; e < 8; ++e) {
      float f = bf2f((unsigned short)h[e]);
      v[j * 8 + e] = f;
      am = fmaxf(am, fabsf(f));
    }
  }
#pragma unroll
  for (int s = 32; s; s >>= 1) am = fmaxf(am, __shfl_xor(am, s));
  if ((t & 63) == 0) red[t >> 6] = am;
  __syncthreads();
  am = fmaxf(fmaxf(red[0], red[1]), fmaxf(red[2], red[3]));
  am = fmaxf(am, 1e-12f);
  const float inv = 127.0f / am;
  i32x4 pk;
#pragma unroll
  for (int j = 0; j < 4; ++j) {
    unsigned p = 0;
#pragma unroll
    for (int e = 0; e < 4; ++e) {
      float qf = rintf(v[j * 4 + e] * inv);
      qf = fminf(fmaxf(qf, -127.f), 127.f);
      p |= ((unsigned)((int)qf & 0xFF)) << (8 * e);
    }
    pk[j] = (int)p;
  }
  *(i32x4*)&mi8[(size_t)row * IN_F + t * 16] = pk;
  if (t == 0) sm[row] = am * (1.0f / 127.0f);
}

// ---------------------------------------------------------------------------
// helpers for gemm256_i8
// ---------------------------------------------------------------------------
static __device__ __forceinline__ void readA4i(i32x4 (&a)[4][2],
                                               const char* __restrict__ base,
                                               const int (&off)[4][2]) {
#pragma unroll
  for (int m = 0; m < 4; ++m)
#pragma unroll
    for (int kk = 0; kk < 2; ++kk)
      a[m][kk] = *(const i32x4*)(base + off[m][kk]);
}
static __device__ __forceinline__ void readB2i(i32x4 (&b)[2][2],
                                               const char* __restrict__ base,
                                               const int (&off)[2][2]) {
#pragma unroll
  for (int n = 0; n < 2; ++n)
#pragma unroll
    for (int kk = 0; kk < 2; ++kk)
      b[n][kk] = *(const i32x4*)(base + off[n][kk]);
}
static __device__ __forceinline__ void mfmaQi(i32x4 (&aq)[4][2],
                                              const i32x4 (&a)[4][2],
                                              const i32x4 (&b)[2][2]) {
#pragma unroll
  for (int m = 0; m < 4; ++m)
#pragma unroll
    for (int n = 0; n < 2; ++n)
#pragma unroll
      for (int kk = 0; kk < 2; ++kk)
        aq[m][n] = __builtin_amdgcn_mfma_i32_16x16x64_i8(a[m][kk], b[n][kk],
                                                         aq[m][n], 0, 0, 0);
}

#define BARR()  __builtin_amdgcn_s_barrier()
#define SCHED() __builtin_amdgcn_sched_barrier(0)
#define LGKM0() asm volatile("s_waitcnt lgkmcnt(0)")
#define PRIO1() __builtin_amdgcn_s_setprio(1)
#define PRIO0() __builtin_amdgcn_s_setprio(0)

// ---------------------------------------------------------------------------
// gemm256_i8: out[t,o] = sx[t]*sm[o] * sum_i xi8[t,i]*mi8[o,i]
// 256x256 tile, K-tile = 128 i8 elements (128 B/row — byte-identical LDS
// geometry, swizzle, and staging to the proven bf16 kernel), 8 waves,
// mfma_i32_16x16x64_i8 (2x bf16 rate), branch-free 2-tile unroll,
// counted vmcnt(6), setprio. nK = 32 -> 15 iters + 2-tile tail.
// ---------------------------------------------------------------------------
__global__ __launch_bounds__(512, 2) void gemm256_i8(
    const char* __restrict__ xi8, const char* __restrict__ mi8,
    const float* __restrict__ sx, const float* __restrict__ sm,
    float* __restrict__ out) {
  extern __shared__ __align__(128) char smem[];
  const int tid  = threadIdx.x;
  const int wid  = tid >> 6;
  const int lane = tid & 63;
  const int wqm  = wid >> 2;  // 0..1 : 64-row slice within a 128x128 quadrant
  const int wqn  = wid & 3;   // 0..3 : 32-col slice

  const int swz = (blockIdx.x & 7) * 64 + (blockIdx.x >> 3);
  const int bm = swz >> 4;   // 0..31 token tiles
  const int bn = swz & 15;   // 0..15 out-feature tiles
  const int row0 = bm * 256;
  const int col0 = bn * 256;

  // ds_read byte offsets (swizzle folded). Rows are 128 B as before.
  int offA[4][2], offB[2][2];
#pragma unroll
  for (int m = 0; m < 4; ++m)
#pragma unroll
    for (int kk = 0; kk < 2; ++kk) {
      int r = wqm * 64 + m * 16 + (lane & 15);
      int cb = kk * 64 + (lane >> 4) * 16;
      offA[m][kk] = r * 128 + (cb ^ ((r & 7) << 4));
    }
#pragma unroll
  for (int n = 0; n < 2; ++n)
#pragma unroll
    for (int kk = 0; kk < 2; ++kk) {
      int r = wqn * 32 + n * 16 + (lane & 15);
      int cb = kk * 64 + (lane >> 4) * 16;
      offB[n][kk] = r * 128 + (cb ^ ((r & 7) << 4));
    }

  // staging: pre-swizzled global source (byte offsets), rows of 128 B
  const int sco = (((lane & 7) ^ (lane >> 3)) << 4);
  const int srw = lane >> 3;
  const char* aP = xi8 + (size_t)(row0 + wid * 16 + srw) * IN_F + sco;
  const char* bP = mi8 + (size_t)(col0 + wid * 16 + srw) * IN_F + sco;
  const char* aH = aP + (size_t)128 * IN_F;
  const char* bH = bP + (size_t)128 * IN_F;
  char* lw = smem + wid * 2048;

  auto STG = [&](const char* __restrict__ g, char* l) {
    gload_lds16(g, l);
    gload_lds16(g + 8 * IN_F, l + 1024);
  };

  i32x4 acc[4][4][2] = {};  // [quadrant][m][n]
  i32x4 a[4][2], b0[2][2], b1[2][2];

  // ---- prologue: t0 {A0,B0,B1,A1} -> buf0; t1 {A0,B0,B1} -> buf1 ----
  STG(aP,        lw + 0);
  STG(bP,        lw + 32768);
  STG(bH,        lw + 49152);
  STG(aH,        lw + 16384);
  STG(aP + 128,  lw + 65536);
  STG(bP + 128,  lw + 98304);
  STG(bH + 128,  lw + 114688);
  asm volatile("s_waitcnt vmcnt(6)");
  SCHED();
  BARR();

  // ---- main loop: 15 iterations, tiles 0..29 ----
  for (int it = 0; it < 15; ++it) {
    // tile tt : buf0
    readA4i(a, smem, offA);
    readB2i(b0, smem + 32768, offB);
    STG(aH + 128, lw + 81920);                // (tt+1).A1 -> buf1.A1
    asm volatile("s_waitcnt lgkmcnt(8)");
    BARR(); LGKM0(); SCHED();
    PRIO1(); mfmaQi(acc[0], a, b0); PRIO0(); SCHED(); BARR();

    readB2i(b1, smem + 49152, offB);
    STG(aP + 256, lw + 0);                    // (tt+2).A0 -> buf0.A0
    BARR(); LGKM0(); SCHED();
    PRIO1(); mfmaQi(acc[1], a, b1); PRIO0(); SCHED(); BARR();

    readA4i(a, smem + 16384, offA);
    STG(bP + 256, lw + 32768);                // (tt+2).B0 -> buf0.B0
    BARR(); LGKM0(); SCHED();
    PRIO1(); mfmaQi(acc[2], a, b1); PRIO0(); SCHED(); BARR();

    STG(bH + 256, lw + 49152);                // (tt+2).B1 -> buf0.B1
    asm volatile("s_waitcnt vmcnt(6)");
    SCHED(); BARR();
    PRIO1(); mfmaQi(acc[3], a, b0); PRIO0(); SCHED(); BARR();

    // tile tt+1 : buf1
    readA4i(a, smem + 65536, offA);
    readB2i(b0, smem + 98304, offB);
    STG(aH + 256, lw + 16384);                // (tt+2).A1 -> buf0.A1
    asm volatile("s_waitcnt lgkmcnt(8)");
    BARR(); LGKM0(); SCHED();
    PRIO1(); mfmaQi(acc[0], a, b0); PRIO0(); SCHED(); BARR();

    readB2i(b1, smem + 114688, offB);
    STG(aP + 384, lw + 65536);                // (tt+3).A0 -> buf1.A0
    BARR(); LGKM0(); SCHED();
    PRIO1(); mfmaQi(acc[1], a, b1); PRIO0(); SCHED(); BARR();

    readA4i(a, smem + 81920, offA);
    STG(bP + 384, lw + 98304);                // (tt+3).B0 -> buf1.B0
    BARR(); LGKM0(); SCHED();
    PRIO1(); mfmaQi(acc[2], a, b1); PRIO0(); SCHED(); BARR();

    STG(bH + 384, lw + 114688);               // (tt+3).B1 -> buf1.B1
    asm volatile("s_waitcnt vmcnt(6)");
    SCHED(); BARR();
    PRIO1(); mfmaQi(acc[3], a, b0); PRIO0(); SCHED(); BARR();

    aP += 256; bP += 256; aH += 256; bH += 256;
  }

  // ---- peeled tail: tile 30 (buf0), tile 31 (buf1) ----
  readA4i(a, smem, offA);
  readB2i(b0, smem + 32768, offB);
  STG(aH + 128, lw + 81920);                  // 31.A1 -> buf1.A1
  asm volatile("s_waitcnt lgkmcnt(8)");
  BARR(); LGKM0(); SCHED();
  PRIO1(); mfmaQi(acc[0], a, b0); PRIO0(); SCHED(); BARR();

  readB2i(b1, smem + 49152, offB);
  BARR(); LGKM0(); SCHED();
  PRIO1(); mfmaQi(acc[1], a, b1); PRIO0(); SCHED(); BARR();

  readA4i(a, smem + 16384, offA);
  BARR(); LGKM0(); SCHED();
  PRIO1(); mfmaQi(acc[2], a, b1); PRIO0(); SCHED(); BARR();

  asm volatile("s_waitcnt vmcnt(0)");
  SCHED(); BARR();
  PRIO1(); mfmaQi(acc[3], a, b0); PRIO0(); SCHED(); BARR();

  readA4i(a, smem + 65536, offA);
  readB2i(b0, smem + 98304, offB);
  BARR(); LGKM0(); SCHED();
  PRIO1(); mfmaQi(acc[0], a, b0); PRIO0(); SCHED(); BARR();

  readB2i(b1, smem + 114688, offB);
  BARR(); LGKM0(); SCHED();
  PRIO1(); mfmaQi(acc[1], a, b1); PRIO0(); SCHED(); BARR();

  readA4i(a, smem + 81920, offA);
  BARR(); LGKM0(); SCHED();
  PRIO1(); mfmaQi(acc[2], a, b1); PRIO0(); SCHED();
  mfmaQi(acc[3], a, b0);

  // ---- epilogue: scale by sx[row]*sm[col] ----
  const int qm_[4] = {0, 0, 1, 1};
  const int qn_[4] = {0, 1, 1, 0};
#pragma unroll
  for (int q = 0; q < 4; ++q) {
#pragma unroll
    for (int m = 0; m < 4; ++m) {
#pragma unroll
      for (int n = 0; n < 2; ++n) {
        int col = col0 + qn_[q] * 128 + wqn * 32 + n * 16 + (lane & 15);
        float smv = sm[col];
#pragma unroll
        for (int rr = 0; rr < 4; ++rr) {
          int row = row0 + qm_[q] * 128 + wqm * 64 + m * 16 + (lane >> 4) * 4 + rr;
          out[(size_t)row * OUT_F + col] =
              (float)acc[q][m][n][rr] * sx[row] * smv;
        }
      }
    }
  }
}

// ---------------------------------------------------------------------------
// Fallback main GEMM (128^2, used only if ws too small): A reg-staged from f32.
// ---------------------------------------------------------------------------
__global__ __launch_bounds__(256) void gemm_main_f(const float* __restrict__ xf,
                                                   const unsigned short* __restrict__ Mw,
                                                   float* __restrict__ out) {
  __shared__ unsigned short lA[128 * 64];
  __shared__ unsigned short lB[128 * 64];
  const int tid  = threadIdx.x;
  const int wid  = tid >> 6;
  const int lane = tid & 63;
  const int nwg = gridDim.x;
  const int cpx = nwg >> 3;
  const int swz = (blockIdx.x & 7) * cpx + (blockIdx.x >> 3);
  const int bm = swz >> 5;
  const int bn = swz & 31;
  const int wm = (wid >> 1) * 64;
  const int wn = (wid & 1) * 64;
  const int row0 = bm * 128;
  const int col0 = bn * 128;

  f32x4 acc[4][4] = {};

  for (int k0 = 0; k0 < IN_F; k0 += 64) {
    __syncthreads();
    const int sr = tid >> 4;
    const int sc = (tid & 15) * 4;
#pragma unroll
    for (int p = 0; p < 8; ++p) {
      int row = p * 16 + sr;
      f32x4 v = *(const f32x4*)&xf[(size_t)(row0 + row) * IN_F + k0 + sc];
      short4v pa;
      pa.x = (short)f2bf(v.x); pa.y = (short)f2bf(v.y);
      pa.z = (short)f2bf(v.z); pa.w = (short)f2bf(v.w);
      *(short4v*)&lA[row * 64 + sc] = pa;
    }
#pragma unroll
    for (int j = 0; j < 4; ++j) {
      int rbase = (wid * 4 + j) * 8;
      const unsigned short* src =
          &Mw[(size_t)(col0 + rbase + (lane >> 3)) * IN_F + k0 + (lane & 7) * 8];
      gload_lds16(src, &lB[rbase * 64]);
    }
    __syncthreads();
#pragma unroll
    for (int kk = 0; kk < 2; ++kk) {
      bf16x8 af[4], bfr[4];
#pragma unroll
      for (int m = 0; m < 4; ++m)
        af[m] = *(const bf16x8*)&lA[(wm + m * 16 + (lane & 15)) * 64 + kk * 32 + (lane >> 4) * 8];
#pragma unroll
      for (int n = 0; n < 4; ++n)
        bfr[n] = *(const bf16x8*)&lB[(wn + n * 16 + (lane & 15)) * 64 + kk * 32 + (lane >> 4) * 8];
#pragma unroll
      for (int m = 0; m < 4; ++m)
#pragma unroll
        for (int n = 0; n < 4; ++n)
          acc[m][n] = __builtin_amdgcn_mfma_f32_16x16x32_bf16(af[m], bfr[n], acc[m][n], 0, 0, 0);
    }
  }

#pragma unroll
  for (int m = 0; m < 4; ++m) {
#pragma unroll
    for (int n = 0; n < 4; ++n) {
      int col = col0 + wn + n * 16 + (lane & 15);
#pragma unroll
      for (int rr = 0; rr < 4; ++rr) {
        int row = row0 + wm + m * 16 + (lane >> 4) * 4 + rr;
        out[(size_t)row * OUT_F + col] = acc[m][n][rr];
      }
    }
  }
}

// ---------------------------------------------------------------------------
extern "C" void kernel_launch(void* const* d_in, const int* in_sizes, int n_in,
                              void* d_out, int out_size, void* d_ws, size_t ws_size,
                              hipStream_t stream) {
  const float* x      = (const float*)d_in[0];
  const int*   q      = (const int*)d_in[1];
  const float* scale  = (const float*)d_in[2];
  const float* minv   = (const float*)d_in[3];
  const float* U      = (const float*)d_in[4];
  const float* S      = (const float*)d_in[5];
  const float* V      = (const float*)d_in[6];
  float* out = (float*)d_out;

  const size_t MB32 = 33554432ull;
  unsigned short* Mw = (unsigned short*)d_ws;                    // 32 MB bf16
  char*  xi8 = (char*)d_ws + MB32;                               // 32 MB
  char*  mi8 = (char*)d_ws + 2 * MB32;                           // 16 MB
  float* sx  = (float*)((char*)d_ws + 2 * MB32 + 16777216);      // 32 KB
  float* sm  = (float*)((char*)d_ws + 2 * MB32 + 16777216 + 32768);  // 16 KB
  const size_t need = 2 * MB32 + 16777216 + 32768 + 16384;

  if (ws_size >= need) {
    (void)hipFuncSetAttribute((const void*)gemm256_i8,
                              hipFuncAttributeMaxDynamicSharedMemorySize,
                              131072);
    prep1<<<dim3(9216), dim3(256), 0, stream>>>(x, xi8, sx, U, V, S, q,
                                                scale, minv, Mw);
    prep2<<<dim3(4096), dim3(256), 0, stream>>>(Mw, mi8, sm);
    gemm256_i8<<<dim3(512), dim3(512), 131072, stream>>>(xi8, mi8, sx, sm, out);
  } else {
    prep1<<<dim3(1024), dim3(256), 0, stream>>>(x, nullptr, nullptr, U, V, S,
                                                q, scale, minv, Mw);
    gemm_main_f<<<dim3(2048), dim3(256), 0, stream>>>(x, Mw, out);
  }
}